// Round 4
// baseline (614.911 us; speedup 1.0000x reference)
//
#include <hip/hip_runtime.h>
#include <hip/hip_bf16.h>

typedef unsigned short u16;
typedef unsigned int   u32;
typedef __attribute__((ext_vector_type(8))) short s16x8;
typedef __attribute__((ext_vector_type(4))) float f32x4;

#define BN_EPS 1e-3f
// problem dims
#define NB 16
#define NC 64
#define NH 160
#define NW 160
#define NE 4
#define NR 16
#define HP 162   // padded H
#define WPD 162  // padded W

// workspace layout (bytes)
#define OFF_XT 0UL
#define SZ_XT  (16UL*162*162*64*2)     // 53,747,712  padded NHWC bf16
#define OFF_WT (OFF_XT + SZ_XT)
#define SZ_WT  (4UL*64*9*64*2)         // 294,912     [E][Co][tap][Ci] bf16
#define OFF_SC (OFF_WT + SZ_WT)        // bn scale [4][64] f32
#define OFF_SH (OFF_SC + 1024UL)       // bn shift [4][64] f32
#define OFF_G  (OFF_SH + 1024UL)       // g [16][64] f32
#define OFF_WE (OFF_G + 4096UL)        // wexp [16][4] f32
#define OFF_GP (OFF_WE + 256UL)        // gpart [1024][800] f32 (3.28 MB)

__device__ __forceinline__ u16 f2bf(float f) {
    u32 u = __builtin_bit_cast(u32, f);
    u += 0x7fffu + ((u >> 16) & 1u);   // round-to-nearest-even
    return (u16)(u >> 16);
}

// ---- zero the 1-pixel halo border of xt ----------------------------------
__global__ void zero_border(u16* __restrict__ xt) {
    int blk = blockIdx.x;              // 16*162
    int hp = blk % 162, b = blk / 162;
    u32* row = (u32*)xt + (((long)b * 162 + hp) * 162) * 32; // 32 u32 per pixel
    int t = threadIdx.x;
    if (hp == 0 || hp == 161) {
        for (int i = t; i < 162 * 32; i += 256) row[i] = 0u;
    } else if (t < 64) {
        int p = (t >> 5) ? 161 : 0;
        row[p * 32 + (t & 31)] = 0u;
    }
}

// ---- weights [E][Co][Ci][3][3] f32 -> [E][Co][tap][Ci] bf16; BN fold -----
__global__ void prep_w(const float* __restrict__ cw, u16* __restrict__ wt,
                       const float* __restrict__ gamma, const float* __restrict__ beta,
                       const float* __restrict__ mean, const float* __restrict__ var,
                       float* __restrict__ scale, float* __restrict__ shift) {
    int idx = blockIdx.x * 256 + threadIdx.x;
    if (idx < 4 * 64 * 9 * 64) {
        int ci = idx & 63;
        int r = idx >> 6;          // (e*64+co)*9 + tap
        int tap = r % 9;
        int ec = r / 9;            // e*64+co
        wt[idx] = f2bf(cw[((long)ec * 64 + ci) * 9 + tap]);
    }
    if (idx < 256) {
        float sc = gamma[idx] * rsqrtf(var[idx] + BN_EPS);
        scale[idx] = sc;
        shift[idx] = beta[idx] - mean[idx] * sc;
    }
}

// ---- x NCHW f32 -> padded NHWC bf16 + router partial sums ----------------
__global__ void prep_x(const float* __restrict__ x, u16* __restrict__ xt,
                       float* __restrict__ gpart) {
    __shared__ float tile[64][33];
    int blk = blockIdx.x;              // b*800 + h*5 + wt5
    int wt5 = blk % 5;
    int tmp = blk / 5;
    int h = tmp % 160, b = tmp / 160;
    int w0 = wt5 * 32;
    int t = threadIdx.x;
    int w = t & 31, c0 = t >> 5;       // c0 in 0..7
#pragma unroll
    for (int i = 0; i < 8; ++i) {
        int c = c0 + 8 * i;
        tile[c][w] = x[(((long)b * 64 + c) * 160 + h) * 160 + w0 + w];
    }
    __syncthreads();
    if (t < 64) {                      // per-channel partial sum over 32 w
        float s = 0.f;
#pragma unroll
        for (int wi = 0; wi < 32; ++wi) s += tile[t][wi];
        gpart[((long)(b * 64 + t)) * 800 + h * 5 + wt5] = s;
    }
    // write NHWC bf16 (padded coords h+1, w+1), coalesced u32 (2 channels)
    u32* xt32 = (u32*)xt;
    long base = ((((long)b * 162 + h + 1) * 162) + (w0 + 1)) * 32; // u32 index
#pragma unroll
    for (int j = 0; j < 4; ++j) {
        int idx = t + 256 * j;         // 0..1023
        int p = idx >> 5, cp = idx & 31;
        float v0 = tile[2 * cp][p], v1 = tile[2 * cp + 1][p];
        xt32[base + p * 32 + cp] = (u32)f2bf(v0) | ((u32)f2bf(v1) << 16);
    }
}

// ---- finish global average pool ------------------------------------------
__global__ void g_reduce(const float* __restrict__ gpart, float* __restrict__ g) {
    int id = blockIdx.x;               // 1024 = b*64+c
    int t = threadIdx.x;
    float s = 0.f;
    for (int i = t; i < 800; i += 256) s += gpart[(long)id * 800 + i];
#pragma unroll
    for (int off = 32; off > 0; off >>= 1) s += __shfl_down(s, off, 64);
    __shared__ float red[4];
    if ((t & 63) == 0) red[t >> 6] = s;
    __syncthreads();
    if (t == 0) g[id] = (red[0] + red[1] + red[2] + red[3]) * (1.f / 25600.f);
}

// ---- router: fc1 -> relu -> fc2 -> softmax -------------------------------
__global__ void router(const float* __restrict__ g, const float* __restrict__ fc1w,
                       const float* __restrict__ fc2w, const float* __restrict__ fc2b,
                       float* __restrict__ wexp) {
    __shared__ float gL[16][64];
    __shared__ float h1[16][16];
    __shared__ float z[16][4];
    int t = threadIdx.x;
    for (int i = t; i < 1024; i += 256) gL[i >> 6][i & 63] = g[i];
    __syncthreads();
    {
        int b = t >> 4, r = t & 15;
        float s = 0.f;
#pragma unroll
        for (int c = 0; c < 64; ++c) s += gL[b][c] * fc1w[r * 64 + c];
        h1[b][r] = fmaxf(s, 0.f);
    }
    __syncthreads();
    if (t < 64) {
        int b = t >> 2, e = t & 3;
        float s = fc2b[e];
#pragma unroll
        for (int r = 0; r < 16; ++r) s += h1[b][r] * fc2w[e * 16 + r];
        z[b][e] = s;
    }
    __syncthreads();
    if (t < 16) {
        int b = t;
        float m = fmaxf(fmaxf(z[b][0], z[b][1]), fmaxf(z[b][2], z[b][3]));
        float e0 = __expf(z[b][0] - m), e1 = __expf(z[b][1] - m);
        float e2 = __expf(z[b][2] - m), e3 = __expf(z[b][3] - m);
        float inv = 1.f / (e0 + e1 + e2 + e3);
        wexp[b * 4 + 0] = e0 * inv; wexp[b * 4 + 1] = e1 * inv;
        wexp[b * 4 + 2] = e2 * inv; wexp[b * 4 + 3] = e3 * inv;
    }
}

// ---- main: 4-expert implicit-GEMM conv + BN + SiLU + weighted sum --------
// grid 1600 = 16 b * 20 htile * 5 wtile ; block 256 (4 waves)
// M = co (64) per wave, N = 64 px per wave (block: 8h x 32w), K = 576.
// A-frags (weights) from GLOBAL (L1/L2-resident thanks to XCD swizzle):
// keeps the LDS pipe for B only (4 ds_read_b128 per 16 MFMA).
__global__ __launch_bounds__(256, 2) void conv_main(
    const u16* __restrict__ xt, const u16* __restrict__ wt,
    const float* __restrict__ scale, const float* __restrict__ shift,
    const float* __restrict__ wexp, float* __restrict__ out) {
    __shared__ u16 xls[340 * 64];       // 340 px x 64 ch bf16 = 43,520 B
    // bijective chunked XCD swizzle (1600 % 8 == 0): XCD k gets 2 batches
    const int o = blockIdx.x;
    const int blk = (o & 7) * 200 + (o >> 3);
    const int wt5 = blk % 5;
    const int tmp = blk / 5;
    const int ht = tmp % 20;
    const int b = tmp / 20;
    const int h0 = ht * 8, w0 = wt5 * 32;
    const int tid = threadIdx.x;
    const int lane = tid & 63;
    const int wv = tid >> 6;
    const int l15 = lane & 15, kl = lane >> 4;

    // stage x halo tile (rows h0..h0+9, cols w0..w0+33), XOR-swizzled:
    // slot(P, cg) = P*8 + (cg ^ (P&7)); P = y*34+x flat pixel, cg = 8-ch group
    {
        const u16* xb = xt + (long)b * HP * WPD * 64;
        for (int c = tid; c < 2720; c += 256) {
            int y = c / 272;
            int rem = c - y * 272;
            int px = rem >> 3, cg = rem & 7;
            int P = y * 34 + px;
            const u16* src = xb + (((long)(h0 + y) * WPD) + (w0 + px)) * 64 + cg * 8;
            s16x8 v = *(const s16x8*)src;
            int slot = (P << 3) + (cg ^ (P & 7));
            *(s16x8*)(&xls[slot << 3]) = v;
        }
    }
    __syncthreads();

    int Pbase[4];
#pragma unroll
    for (int nf = 0; nf < 4; ++nf)
        Pbase[nf] = (2 * wv + (nf >> 1)) * 34 + (nf & 1) * 16 + l15;

    f32x4 oacc[4][4];
#pragma unroll
    for (int i = 0; i < 4; ++i)
#pragma unroll
        for (int j = 0; j < 4; ++j) oacc[i][j] = (f32x4)(0.f);

#pragma unroll 1
    for (int e = 0; e < 4; ++e) {
        const u16* wte = wt + ((long)e * 64) * 576;
        const u16* ab0 = wte + (0 * 16 + l15) * 576 + (kl << 3);
        const u16* ab1 = wte + (1 * 16 + l15) * 576 + (kl << 3);
        const u16* ab2 = wte + (2 * 16 + l15) * 576 + (kl << 3);
        const u16* ab3 = wte + (3 * 16 + l15) * 576 + (kl << 3);
        f32x4 acc[4][4];
#pragma unroll
        for (int i = 0; i < 4; ++i)
#pragma unroll
            for (int j = 0; j < 4; ++j) acc[i][j] = (f32x4)(0.f);

        // software pipeline: global A-frags prefetched one chunk ahead;
        // B-frags (LDS) read just-in-time.
        s16x8 a0 = *(const s16x8*)(ab0);
        s16x8 a1 = *(const s16x8*)(ab1);
        s16x8 a2 = *(const s16x8*)(ab2);
        s16x8 a3 = *(const s16x8*)(ab3);

#pragma unroll
        for (int chunk = 0; chunk < 18; ++chunk) {
            const int tap = chunk >> 1, cg2 = chunk & 1;
            const int dy = tap / 3, dx = tap - 3 * dy;
            const int poff = dy * 34 + dx;
            const int cgr = (cg2 << 2) + kl;
            s16x8 an0 = a0, an1 = a1, an2 = a2, an3 = a3;
            if (chunk < 17) {
                an0 = *(const s16x8*)(ab0 + (chunk + 1) * 32);
                an1 = *(const s16x8*)(ab1 + (chunk + 1) * 32);
                an2 = *(const s16x8*)(ab2 + (chunk + 1) * 32);
                an3 = *(const s16x8*)(ab3 + (chunk + 1) * 32);
            }
            s16x8 bf0, bf1, bf2, bf3;
            {
                int P = Pbase[0] + poff;
                bf0 = *(const s16x8*)(&xls[((P << 3) + (cgr ^ (P & 7))) << 3]);
            }
            {
                int P = Pbase[1] + poff;
                bf1 = *(const s16x8*)(&xls[((P << 3) + (cgr ^ (P & 7))) << 3]);
            }
            {
                int P = Pbase[2] + poff;
                bf2 = *(const s16x8*)(&xls[((P << 3) + (cgr ^ (P & 7))) << 3]);
            }
            {
                int P = Pbase[3] + poff;
                bf3 = *(const s16x8*)(&xls[((P << 3) + (cgr ^ (P & 7))) << 3]);
            }
            acc[0][0] = __builtin_amdgcn_mfma_f32_16x16x32_bf16(a0, bf0, acc[0][0], 0, 0, 0);
            acc[1][0] = __builtin_amdgcn_mfma_f32_16x16x32_bf16(a1, bf0, acc[1][0], 0, 0, 0);
            acc[2][0] = __builtin_amdgcn_mfma_f32_16x16x32_bf16(a2, bf0, acc[2][0], 0, 0, 0);
            acc[3][0] = __builtin_amdgcn_mfma_f32_16x16x32_bf16(a3, bf0, acc[3][0], 0, 0, 0);
            acc[0][1] = __builtin_amdgcn_mfma_f32_16x16x32_bf16(a0, bf1, acc[0][1], 0, 0, 0);
            acc[1][1] = __builtin_amdgcn_mfma_f32_16x16x32_bf16(a1, bf1, acc[1][1], 0, 0, 0);
            acc[2][1] = __builtin_amdgcn_mfma_f32_16x16x32_bf16(a2, bf1, acc[2][1], 0, 0, 0);
            acc[3][1] = __builtin_amdgcn_mfma_f32_16x16x32_bf16(a3, bf1, acc[3][1], 0, 0, 0);
            acc[0][2] = __builtin_amdgcn_mfma_f32_16x16x32_bf16(a0, bf2, acc[0][2], 0, 0, 0);
            acc[1][2] = __builtin_amdgcn_mfma_f32_16x16x32_bf16(a1, bf2, acc[1][2], 0, 0, 0);
            acc[2][2] = __builtin_amdgcn_mfma_f32_16x16x32_bf16(a2, bf2, acc[2][2], 0, 0, 0);
            acc[3][2] = __builtin_amdgcn_mfma_f32_16x16x32_bf16(a3, bf2, acc[3][2], 0, 0, 0);
            acc[0][3] = __builtin_amdgcn_mfma_f32_16x16x32_bf16(a0, bf3, acc[0][3], 0, 0, 0);
            acc[1][3] = __builtin_amdgcn_mfma_f32_16x16x32_bf16(a1, bf3, acc[1][3], 0, 0, 0);
            acc[2][3] = __builtin_amdgcn_mfma_f32_16x16x32_bf16(a2, bf3, acc[2][3], 0, 0, 0);
            acc[3][3] = __builtin_amdgcn_mfma_f32_16x16x32_bf16(a3, bf3, acc[3][3], 0, 0, 0);
            a0 = an0; a1 = an1; a2 = an2; a3 = an3;
        }
        // epilogue: BN + SiLU + router weight
        const float we = wexp[(b << 2) + e];
#pragma unroll
        for (int mf = 0; mf < 4; ++mf) {
#pragma unroll
            for (int j = 0; j < 4; ++j) {
                const int co = mf * 16 + (kl << 2) + j;
                const float sc = scale[(e << 6) + co];
                const float sh = shift[(e << 6) + co];
#pragma unroll
                for (int nf = 0; nf < 4; ++nf) {
                    float y = acc[mf][nf][j] * sc + sh;
                    float s = y * __builtin_amdgcn_rcpf(1.f + __expf(-y));
                    oacc[mf][nf][j] += we * s;
                }
            }
        }
    }
    // store NCHW f32: per instr 4 co-rows x 16 consecutive w (64B segments)
#pragma unroll
    for (int mf = 0; mf < 4; ++mf) {
#pragma unroll
        for (int nf = 0; nf < 4; ++nf) {
            const int y = h0 + 2 * wv + (nf >> 1);
            const int x = w0 + (nf & 1) * 16 + l15;
#pragma unroll
            for (int j = 0; j < 4; ++j) {
                const int co = mf * 16 + (kl << 2) + j;
                out[(((long)(b * 64 + co)) * 160 + y) * 160 + x] = oacc[mf][nf][j];
            }
        }
    }
}

extern "C" void kernel_launch(void* const* d_in, const int* in_sizes, int n_in,
                              void* d_out, int out_size, void* d_ws, size_t ws_size,
                              hipStream_t stream) {
    const float* x = (const float*)d_in[0];
    const float* fc1w = (const float*)d_in[1];
    const float* fc2w = (const float*)d_in[2];
    const float* fc2b = (const float*)d_in[3];
    const float* convw = (const float*)d_in[4];
    const float* gamma = (const float*)d_in[5];
    const float* beta = (const float*)d_in[6];
    const float* mean = (const float*)d_in[7];
    const float* var = (const float*)d_in[8];
    float* out = (float*)d_out;
    char* ws = (char*)d_ws;
    u16* xt = (u16*)(ws + OFF_XT);
    u16* wtb = (u16*)(ws + OFF_WT);
    float* scale = (float*)(ws + OFF_SC);
    float* shift = (float*)(ws + OFF_SH);
    float* g = (float*)(ws + OFF_G);
    float* wexp = (float*)(ws + OFF_WE);
    float* gpart = (float*)(ws + OFF_GP);

    zero_border<<<16 * 162, 256, 0, stream>>>(xt);
    prep_w<<<576, 256, 0, stream>>>(convw, wtb, gamma, beta, mean, var, scale, shift);
    prep_x<<<12800, 256, 0, stream>>>(x, xt, gpart);
    g_reduce<<<1024, 256, 0, stream>>>(gpart, g);
    router<<<1, 256, 0, stream>>>(g, fc1w, fc2w, fc2b, wexp);
    conv_main<<<1600, 256, 0, stream>>>(xt, wtb, scale, shift, wexp, out);
}

// Round 5
// 180.990 us; speedup vs baseline: 3.3975x; 3.3975x over previous
//
#include <hip/hip_runtime.h>
#include <hip/hip_bf16.h>

typedef unsigned short u16;
typedef unsigned int   u32;
typedef __attribute__((ext_vector_type(8))) short s16x8;
typedef __attribute__((ext_vector_type(4))) float f32x4;

#define BN_EPS 1e-3f
// problem dims
#define NB 16
#define NC 64
#define NH 160
#define NW 160
#define NE 4
#define NR 16
#define HP 162   // padded H
#define WPD 162  // padded W

// workspace layout (bytes)
#define OFF_XT 0UL
#define SZ_XT  (16UL*162*162*64*2)     // 53,747,712  padded NHWC bf16
#define OFF_WT (OFF_XT + SZ_XT)
#define SZ_WT  (4UL*64*9*64*2)         // 294,912  [e][ch][tap][cio][co][8ci] bf16
#define OFF_SC (OFF_WT + SZ_WT)        // bn scale [4][64] f32
#define OFF_SH (OFF_SC + 1024UL)       // bn shift [4][64] f32
#define OFF_G  (OFF_SH + 1024UL)       // g [16][64] f32
#define OFF_WE (OFF_G + 4096UL)        // wexp [16][4] f32
#define OFF_GP (OFF_WE + 256UL)        // gpart [1024][800] f32 (3.28 MB)

// conv_main LDS partition (dynamic, 80,384 B total -> 2 blocks/CU)
#define XLS_BYTES (340 * 64 * 2)       // 43,520
#define WLS_BYTES (2304 * 16)          // 36,864 = 36 k-octets x 64 co x 16 B
#define SMEM_TOTAL (XLS_BYTES + WLS_BYTES)

__device__ __forceinline__ u16 f2bf(float f) {
    u32 u = __builtin_bit_cast(u32, f);
    u += 0x7fffu + ((u >> 16) & 1u);   // round-to-nearest-even
    return (u16)(u >> 16);
}

// ---- zero the 1-pixel halo border of xt ----------------------------------
__global__ void zero_border(u16* __restrict__ xt) {
    int blk = blockIdx.x;              // 16*162
    int hp = blk % 162, b = blk / 162;
    u32* row = (u32*)xt + (((long)b * 162 + hp) * 162) * 32; // 32 u32 per pixel
    int t = threadIdx.x;
    if (hp == 0 || hp == 161) {
        for (int i = t; i < 162 * 32; i += 256) row[i] = 0u;
    } else if (t < 64) {
        int p = (t >> 5) ? 161 : 0;
        row[p * 32 + (t & 31)] = 0u;
    }
}

// ---- weights [E][Co][Ci][3][3] f32 -> [e][ch][tap][cio][co][8ci] bf16 ----
// (so each (e,ch) half-ci panel of 36,864 B is one linear chunk whose
//  16 B octets land at [k-octet t=tap*4+cio][co] for global_load_lds)
__global__ void prep_w(const float* __restrict__ cw, u16* __restrict__ wt,
                       const float* __restrict__ gamma, const float* __restrict__ beta,
                       const float* __restrict__ mean, const float* __restrict__ var,
                       float* __restrict__ scale, float* __restrict__ shift) {
    int idx = blockIdx.x * 256 + threadIdx.x;
    if (idx < 4 * 2 * 9 * 4 * 64 * 8) {
        int cin = idx & 7;
        int t = idx >> 3;
        int co = t & 63; t >>= 6;
        int cio = t & 3; t >>= 2;
        int tap = t % 9; t /= 9;
        int ch = t & 1;
        int e = t >> 1;
        int ci = ch * 32 + cio * 8 + cin;
        wt[idx] = f2bf(cw[(((long)(e * 64 + co)) * 64 + ci) * 9 + tap]);
    }
    if (idx < 256) {
        float sc = gamma[idx] * rsqrtf(var[idx] + BN_EPS);
        scale[idx] = sc;
        shift[idx] = beta[idx] - mean[idx] * sc;
    }
}

// ---- x NCHW f32 -> padded NHWC bf16 + router partial sums ----------------
__global__ void prep_x(const float* __restrict__ x, u16* __restrict__ xt,
                       float* __restrict__ gpart) {
    __shared__ float tile[64][33];
    int blk = blockIdx.x;              // b*800 + h*5 + wt5
    int wt5 = blk % 5;
    int tmp = blk / 5;
    int h = tmp % 160, b = tmp / 160;
    int w0 = wt5 * 32;
    int t = threadIdx.x;
    int w = t & 31, c0 = t >> 5;       // c0 in 0..7
#pragma unroll
    for (int i = 0; i < 8; ++i) {
        int c = c0 + 8 * i;
        tile[c][w] = x[(((long)b * 64 + c) * 160 + h) * 160 + w0 + w];
    }
    __syncthreads();
    if (t < 64) {                      // per-channel partial sum over 32 w
        float s = 0.f;
#pragma unroll
        for (int wi = 0; wi < 32; ++wi) s += tile[t][wi];
        gpart[((long)(b * 64 + t)) * 800 + h * 5 + wt5] = s;
    }
    // write NHWC bf16 (padded coords h+1, w+1), coalesced u32 (2 channels)
    u32* xt32 = (u32*)xt;
    long base = ((((long)b * 162 + h + 1) * 162) + (w0 + 1)) * 32; // u32 index
#pragma unroll
    for (int j = 0; j < 4; ++j) {
        int idx = t + 256 * j;         // 0..1023
        int p = idx >> 5, cp = idx & 31;
        float v0 = tile[2 * cp][p], v1 = tile[2 * cp + 1][p];
        xt32[base + p * 32 + cp] = (u32)f2bf(v0) | ((u32)f2bf(v1) << 16);
    }
}

// ---- finish global average pool ------------------------------------------
__global__ void g_reduce(const float* __restrict__ gpart, float* __restrict__ g) {
    int id = blockIdx.x;               // 1024 = b*64+c
    int t = threadIdx.x;
    float s = 0.f;
    for (int i = t; i < 800; i += 256) s += gpart[(long)id * 800 + i];
#pragma unroll
    for (int off = 32; off > 0; off >>= 1) s += __shfl_down(s, off, 64);
    __shared__ float red[4];
    if ((t & 63) == 0) red[t >> 6] = s;
    __syncthreads();
    if (t == 0) g[id] = (red[0] + red[1] + red[2] + red[3]) * (1.f / 25600.f);
}

// ---- router: fc1 -> relu -> fc2 -> softmax -------------------------------
__global__ void router(const float* __restrict__ g, const float* __restrict__ fc1w,
                       const float* __restrict__ fc2w, const float* __restrict__ fc2b,
                       float* __restrict__ wexp) {
    __shared__ float gL[16][64];
    __shared__ float h1[16][16];
    __shared__ float z[16][4];
    int t = threadIdx.x;
    for (int i = t; i < 1024; i += 256) gL[i >> 6][i & 63] = g[i];
    __syncthreads();
    {
        int b = t >> 4, r = t & 15;
        float s = 0.f;
#pragma unroll
        for (int c = 0; c < 64; ++c) s += gL[b][c] * fc1w[r * 64 + c];
        h1[b][r] = fmaxf(s, 0.f);
    }
    __syncthreads();
    if (t < 64) {
        int b = t >> 2, e = t & 3;
        float s = fc2b[e];
#pragma unroll
        for (int r = 0; r < 16; ++r) s += h1[b][r] * fc2w[e * 16 + r];
        z[b][e] = s;
    }
    __syncthreads();
    if (t < 16) {
        int b = t;
        float m = fmaxf(fmaxf(z[b][0], z[b][1]), fmaxf(z[b][2], z[b][3]));
        float e0 = __expf(z[b][0] - m), e1 = __expf(z[b][1] - m);
        float e2 = __expf(z[b][2] - m), e3 = __expf(z[b][3] - m);
        float inv = 1.f / (e0 + e1 + e2 + e3);
        wexp[b * 4 + 0] = e0 * inv; wexp[b * 4 + 1] = e1 * inv;
        wexp[b * 4 + 2] = e2 * inv; wexp[b * 4 + 3] = e3 * inv;
    }
}

// ---- main: 4-expert implicit-GEMM conv + BN + SiLU + weighted sum --------
// grid 1600 = 16 b * 20 htile * 5 wtile ; block 256 (4 waves)
// Wave tile: M = 64 co (4 frags), N = 64 px (4 frags) -> 8 ds_read_b128
// per 16 MFMA (0.031 LDS-B/FLOP). Weights staged per (e, ci-half) as a
// 64co x 288K panel (36,864 B) via global_load_lds width-16 (linear).
__global__ __launch_bounds__(256, 2) void conv_main(
    const u16* __restrict__ xt, const u16* __restrict__ wt,
    const float* __restrict__ scale, const float* __restrict__ shift,
    const float* __restrict__ wexp, float* __restrict__ out) {
    extern __shared__ char smem[];
    u16* xls = (u16*)smem;                       // 340 px x 64 ch (swizzled)
    u16* wls = (u16*)(smem + XLS_BYTES);         // [t=36 k-octets][64 co] 16 B

    // bijective chunked XCD swizzle (1600 % 8 == 0): XCD k gets 2 batches
    const int o = blockIdx.x;
    const int blk = (o & 7) * 200 + (o >> 3);
    const int wt5 = blk % 5;
    const int tmp = blk / 5;
    const int ht = tmp % 20;
    const int b = tmp / 20;
    const int h0 = ht * 8, w0 = wt5 * 32;
    const int tid = threadIdx.x;
    const int lane = tid & 63;
    const int wv = tid >> 6;
    const int l15 = lane & 15, kl = lane >> 4;

    // stage x halo tile (rows h0..h0+9, cols w0..w0+33), XOR-swizzled:
    // slot(P, cg) = P*8 + (cg ^ (P&7)); P = y*34+x flat pixel, cg = 8-ch group
    {
        const u16* xb = xt + (long)b * HP * WPD * 64;
        for (int c = tid; c < 2720; c += 256) {
            int y = c / 272;
            int rem = c - y * 272;
            int px = rem >> 3, cg = rem & 7;
            int P = y * 34 + px;
            const u16* src = xb + (((long)(h0 + y) * WPD) + (w0 + px)) * 64 + cg * 8;
            s16x8 v = *(const s16x8*)src;
            int slot = (P << 3) + (cg ^ (P & 7));
            *(s16x8*)(&xls[slot << 3]) = v;
        }
    }

    int Pbase[4];
#pragma unroll
    for (int nf = 0; nf < 4; ++nf)
        Pbase[nf] = (2 * wv + (nf >> 1)) * 34 + (nf & 1) * 16 + l15;

    f32x4 oacc[4][4];
#pragma unroll
    for (int i = 0; i < 4; ++i)
#pragma unroll
        for (int j = 0; j < 4; ++j) oacc[i][j] = (f32x4)(0.f);

#pragma unroll 1
    for (int e = 0; e < 4; ++e) {
        f32x4 acc[4][4];
#pragma unroll
        for (int i = 0; i < 4; ++i)
#pragma unroll
            for (int j = 0; j < 4; ++j) acc[i][j] = (f32x4)(0.f);

#pragma unroll 1
        for (int ch = 0; ch < 2; ++ch) {
            // protect wls (and, first time, xls) from in-flight readers
            __syncthreads();
            // stage weight half-ci panel: 2304 octets, linear DMA to LDS
            {
                const u16* wsrc = wt + ((long)(e * 2 + ch)) * 2304 * 8;
#pragma unroll
                for (int r = 0; r < 9; ++r) {
                    int oo = r * 256 + tid;      // octet index
                    __builtin_amdgcn_global_load_lds(
                        (const __attribute__((address_space(1))) void*)(wsrc + oo * 8),
                        (__attribute__((address_space(3))) void*)(wls + oo * 8),
                        16, 0, 0);
                }
            }
            __syncthreads();   // compiler drains vmcnt(0) before barrier

            const int cgr = (ch << 2) + kl;      // x ci-octet for this half
#pragma unroll
            for (int tap = 0; tap < 9; ++tap) {
                const int dy = tap / 3, dx = tap - 3 * dy;
                const int poff = dy * 34 + dx;
                // A-frags: [t = tap*4+kl][co = mf*16+l15]
                const int abase = ((tap * 4 + kl) * 64 + l15) * 8;
                s16x8 af0 = *(const s16x8*)(&wls[abase]);
                s16x8 af1 = *(const s16x8*)(&wls[abase + 16 * 8]);
                s16x8 af2 = *(const s16x8*)(&wls[abase + 32 * 8]);
                s16x8 af3 = *(const s16x8*)(&wls[abase + 48 * 8]);
                s16x8 bf0, bf1, bf2, bf3;
                {
                    int P = Pbase[0] + poff;
                    bf0 = *(const s16x8*)(&xls[((P << 3) + (cgr ^ (P & 7))) << 3]);
                }
                {
                    int P = Pbase[1] + poff;
                    bf1 = *(const s16x8*)(&xls[((P << 3) + (cgr ^ (P & 7))) << 3]);
                }
                {
                    int P = Pbase[2] + poff;
                    bf2 = *(const s16x8*)(&xls[((P << 3) + (cgr ^ (P & 7))) << 3]);
                }
                {
                    int P = Pbase[3] + poff;
                    bf3 = *(const s16x8*)(&xls[((P << 3) + (cgr ^ (P & 7))) << 3]);
                }
                acc[0][0] = __builtin_amdgcn_mfma_f32_16x16x32_bf16(af0, bf0, acc[0][0], 0, 0, 0);
                acc[1][0] = __builtin_amdgcn_mfma_f32_16x16x32_bf16(af1, bf0, acc[1][0], 0, 0, 0);
                acc[2][0] = __builtin_amdgcn_mfma_f32_16x16x32_bf16(af2, bf0, acc[2][0], 0, 0, 0);
                acc[3][0] = __builtin_amdgcn_mfma_f32_16x16x32_bf16(af3, bf0, acc[3][0], 0, 0, 0);
                acc[0][1] = __builtin_amdgcn_mfma_f32_16x16x32_bf16(af0, bf1, acc[0][1], 0, 0, 0);
                acc[1][1] = __builtin_amdgcn_mfma_f32_16x16x32_bf16(af1, bf1, acc[1][1], 0, 0, 0);
                acc[2][1] = __builtin_amdgcn_mfma_f32_16x16x32_bf16(af2, bf1, acc[2][1], 0, 0, 0);
                acc[3][1] = __builtin_amdgcn_mfma_f32_16x16x32_bf16(af3, bf1, acc[3][1], 0, 0, 0);
                acc[0][2] = __builtin_amdgcn_mfma_f32_16x16x32_bf16(af0, bf2, acc[0][2], 0, 0, 0);
                acc[1][2] = __builtin_amdgcn_mfma_f32_16x16x32_bf16(af1, bf2, acc[1][2], 0, 0, 0);
                acc[2][2] = __builtin_amdgcn_mfma_f32_16x16x32_bf16(af2, bf2, acc[2][2], 0, 0, 0);
                acc[3][2] = __builtin_amdgcn_mfma_f32_16x16x32_bf16(af3, bf2, acc[3][2], 0, 0, 0);
                acc[0][3] = __builtin_amdgcn_mfma_f32_16x16x32_bf16(af0, bf3, acc[0][3], 0, 0, 0);
                acc[1][3] = __builtin_amdgcn_mfma_f32_16x16x32_bf16(af1, bf3, acc[1][3], 0, 0, 0);
                acc[2][3] = __builtin_amdgcn_mfma_f32_16x16x32_bf16(af2, bf3, acc[2][3], 0, 0, 0);
                acc[3][3] = __builtin_amdgcn_mfma_f32_16x16x32_bf16(af3, bf3, acc[3][3], 0, 0, 0);
            }
        }
        // epilogue: BN + SiLU + router weight
        const float we = wexp[(b << 2) + e];
#pragma unroll
        for (int mf = 0; mf < 4; ++mf) {
#pragma unroll
            for (int j = 0; j < 4; ++j) {
                const int co = mf * 16 + (kl << 2) + j;
                const float sc = scale[(e << 6) + co];
                const float sh = shift[(e << 6) + co];
#pragma unroll
                for (int nf = 0; nf < 4; ++nf) {
                    float y = acc[mf][nf][j] * sc + sh;
                    float s = y * __builtin_amdgcn_rcpf(1.f + __expf(-y));
                    oacc[mf][nf][j] += we * s;
                }
            }
        }
    }
    // store NCHW f32: per instr 4 co-rows x 16 consecutive w (64B segments)
#pragma unroll
    for (int mf = 0; mf < 4; ++mf) {
#pragma unroll
        for (int nf = 0; nf < 4; ++nf) {
            const int y = h0 + 2 * wv + (nf >> 1);
            const int x = w0 + (nf & 1) * 16 + l15;
#pragma unroll
            for (int j = 0; j < 4; ++j) {
                const int co = mf * 16 + (kl << 2) + j;
                out[(((long)(b * 64 + co)) * 160 + y) * 160 + x] = oacc[mf][nf][j];
            }
        }
    }
}

extern "C" void kernel_launch(void* const* d_in, const int* in_sizes, int n_in,
                              void* d_out, int out_size, void* d_ws, size_t ws_size,
                              hipStream_t stream) {
    const float* x = (const float*)d_in[0];
    const float* fc1w = (const float*)d_in[1];
    const float* fc2w = (const float*)d_in[2];
    const float* fc2b = (const float*)d_in[3];
    const float* convw = (const float*)d_in[4];
    const float* gamma = (const float*)d_in[5];
    const float* beta = (const float*)d_in[6];
    const float* mean = (const float*)d_in[7];
    const float* var = (const float*)d_in[8];
    float* out = (float*)d_out;
    char* ws = (char*)d_ws;
    u16* xt = (u16*)(ws + OFF_XT);
    u16* wtb = (u16*)(ws + OFF_WT);
    float* scale = (float*)(ws + OFF_SC);
    float* shift = (float*)(ws + OFF_SH);
    float* g = (float*)(ws + OFF_G);
    float* wexp = (float*)(ws + OFF_WE);
    float* gpart = (float*)(ws + OFF_GP);

    hipFuncSetAttribute((const void*)conv_main,
                        hipFuncAttributeMaxDynamicSharedMemorySize, SMEM_TOTAL);

    zero_border<<<16 * 162, 256, 0, stream>>>(xt);
    prep_w<<<576, 256, 0, stream>>>(convw, wtb, gamma, beta, mean, var, scale, shift);
    prep_x<<<12800, 256, 0, stream>>>(x, xt, gpart);
    g_reduce<<<1024, 256, 0, stream>>>(gpart, g);
    router<<<1, 256, 0, stream>>>(g, fc1w, fc2w, fc2b, wexp);
    conv_main<<<1600, 256, SMEM_TOTAL, stream>>>(xt, wtb, scale, shift, wexp, out);
}